// Round 3
// baseline (270.483 us; speedup 1.0000x reference)
//
#include <hip/hip_runtime.h>

#define TRAJ_LEN 2048
#define BLOCK 256
#define RPT 8                      // rows per thread = 2048/256
#define ROW_FLOATS 6
#define TRAJ_FLOATS (TRAJ_LEN * ROW_FLOATS)   // 12288 floats = 48 KB

__global__ __launch_bounds__(BLOCK) void sig_kernel(const float* __restrict__ traj,
                                                    float* __restrict__ out) {
    const int b = blockIdx.x;
    const int t = threadIdx.x;
    const float* base = traj + (size_t)b * TRAJ_FLOATS;

    // ---- load 8 consecutive rows (48 floats = 12 float4, 16B-aligned: 192B/thread) ----
    float4 q[12];
    {
        const float4* g4 = (const float4*)base + t * 12;
#pragma unroll
        for (int i = 0; i < 12; ++i) q[i] = g4[i];
    }

    // boundary prev row (global row 8t-1), t > 0
    float p_px = 0.f, p_py = 0.f, p_vx = 0.f, p_vy = 0.f, p_ax = 0.f, p_ay = 0.f;
    if (t > 0) {
        const float2 pp = *(const float2*)(base + t * 48 - 6);  // 8B-aligned
        const float4 pv = *(const float4*)(base + t * 48 - 4);  // 16B-aligned
        p_px = pp.x; p_py = pp.y;
        p_vx = pv.x; p_vy = pv.y; p_ax = pv.z; p_ay = pv.w;
    }
    float pn_prev = sqrtf(p_px * p_px + p_py * p_py);

    float curv = 0.f, cnt = 0.f;
    float dvel = 0.f, jerk = 0.f;
    float ssum = 0.f, ssq = 0.f;
    float fsum = 0.f, fsq = 0.f;

    const float* f = (const float*)q;   // fully-unrolled constant indexing -> stays in VGPRs
#pragma unroll
    for (int j = 0; j < RPT; ++j) {
        float px = f[6 * j + 0], py = f[6 * j + 1];
        float vx = f[6 * j + 2], vy = f[6 * j + 3];
        float ax = f[6 * j + 4], ay = f[6 * j + 5];

        float s2 = vx * vx + vy * vy;
        ssum += sqrtf(s2);  ssq += s2;
        float f2 = ax * ax + ay * ay;
        fsum += sqrtf(f2);  fsq += f2;

        float pn_cur = sqrtf(px * px + py * py);

        bool has_prev  = (t > 0) || (j >= 1);   // global row >= 1
        bool has_prev2 = (t > 0) || (j >= 2);   // global row >= 2
        if (has_prev) {
            dvel += fabsf(vx - p_vx) + fabsf(vy - p_vy);
            jerk += fabsf(ax - p_ax) + fabsf(ay - p_ay);
        }
        if (has_prev2) {
            // cumsum telescopes: v1 = traj[r-1,:2], v2 = traj[r,:2]
            float cross = p_px * py - p_py * px;
            float n = pn_prev * pn_cur;
            if (n > 1e-6f) {
                curv += fabsf(cross) / n;
                cnt += 1.f;
            }
        }

        p_px = px; p_py = py; p_vx = vx; p_vy = vy; p_ax = ax; p_ay = ay;
        pn_prev = pn_cur;
    }

    // ---- wave butterfly reduce (64 lanes) ----
#pragma unroll
    for (int off = 32; off > 0; off >>= 1) {
        curv += __shfl_down(curv, off);
        cnt  += __shfl_down(cnt,  off);
        dvel += __shfl_down(dvel, off);
        jerk += __shfl_down(jerk, off);
        ssum += __shfl_down(ssum, off);
        ssq  += __shfl_down(ssq,  off);
        fsum += __shfl_down(fsum, off);
        fsq  += __shfl_down(fsq,  off);
    }

    __shared__ float red[BLOCK / 64][8];
    const int lane = t & 63;
    const int wid  = t >> 6;
    if (lane == 0) {
        red[wid][0] = curv; red[wid][1] = cnt;
        red[wid][2] = dvel; red[wid][3] = jerk;
        red[wid][4] = ssum; red[wid][5] = ssq;
        red[wid][6] = fsum; red[wid][7] = fsq;
    }
    __syncthreads();

    if (t == 0) {
        float C = 0.f, N = 0.f, D = 0.f, J = 0.f, S = 0.f, S2 = 0.f, F = 0.f, F2 = 0.f;
#pragma unroll
        for (int w = 0; w < BLOCK / 64; ++w) {
            C  += red[w][0]; N  += red[w][1];
            D  += red[w][2]; J  += red[w][3];
            S  += red[w][4]; S2 += red[w][5];
            F  += red[w][6]; F2 += red[w][7];
        }
        const float inv_pairs = 1.f / (float)(2 * (TRAJ_LEN - 1));
        const float invT = 1.f / (float)TRAJ_LEN;

        float path_curvature = (N > 0.f) ? (C / N) : 0.f;
        float velocity_smoothness = 1.f / (1.f + D * inv_pairs);
        float acceleration_jerk = J * inv_pairs;

        float ms = S * invT;
        float vvar = S2 * invT - ms * ms;
        vvar = vvar > 0.f ? vvar : 0.f;
        float movement_rhythm = sqrtf(vvar) / (ms + 1e-6f);

        float mf = F * invT;
        float fvar = F2 * invT - mf * mf;
        fvar = fvar > 0.f ? fvar : 0.f;
        float force_modulation = sqrtf(fvar) / (mf + 1e-6f);

        float* o = out + (size_t)b * 5;
        o[0] = path_curvature;
        o[1] = velocity_smoothness;
        o[2] = acceleration_jerk;
        o[3] = movement_rhythm;
        o[4] = force_modulation;
    }
}

extern "C" void kernel_launch(void* const* d_in, const int* in_sizes, int n_in,
                              void* d_out, int out_size, void* d_ws, size_t ws_size,
                              hipStream_t stream) {
    const float* traj = (const float*)d_in[0];
    float* out = (float*)d_out;
    const int B = in_sizes[0] / TRAJ_FLOATS;   // 4096
    sig_kernel<<<dim3(B), dim3(BLOCK), 0, stream>>>(traj, out);
}